// Round 1
// baseline (141.024 us; speedup 1.0000x reference)
//
#include <hip/hip_runtime.h>

#define NB 8
#define NN 2048
#define ND 128

typedef float f32x4 __attribute__((ext_vector_type(4)));
typedef __bf16 bf16x8 __attribute__((ext_vector_type(8)));
typedef unsigned short u16x4 __attribute__((ext_vector_type(4)));

__device__ __forceinline__ unsigned short f2bf(float f) {
  unsigned u = __builtin_bit_cast(unsigned, f);
  u = (u + 0x7FFFu + ((u >> 16) & 1u)) >> 16;
  return (unsigned short)u;
}

// K1: h = x @ W^T + b (fp32). Emit hn = L2norm(h) as bf16 [B*N, D] (row-major)
// and hT = h as bf16 [B, D, N] (feature-major, PV B-operand layout).
__global__ __launch_bounds__(512, 2) void k_linear(
    const float* __restrict__ x, const float* __restrict__ W,
    const float* __restrict__ bias,
    unsigned short* __restrict__ hn, unsigned short* __restrict__ hT) {
  // xs: x transposed [k][row], wt: W transposed [k][o]; XOR-swizzle columns by
  // (k & 28) so the scalar transpose-writes spread across banks while float4
  // reads stay 16B-aligned and contiguous.
  __shared__ __align__(16) float xs[128][68];
  __shared__ __align__(16) float wt[128][128];
  const int tid = threadIdx.x;
  const int rbase = blockIdx.x * 64;       // global row base (64 rows/block)
  const int b = rbase >> 11;
  const int nb = rbase & (NN - 1);

#pragma unroll
  for (int j = 0; j < 4; ++j) {            // stage x: 64 rows x 128 k
    int f = tid + j * 512;
    int row = f >> 5;
    int kc = (f & 31) << 2;
    f32x4 v = *reinterpret_cast<const f32x4*>(&x[(size_t)(rbase + row) * ND + kc]);
#pragma unroll
    for (int i2 = 0; i2 < 4; ++i2) {
      int k = kc + i2;
      xs[k][row ^ (k & 28)] = v[i2];
    }
  }
#pragma unroll
  for (int j = 0; j < 8; ++j) {            // stage W: 128 o x 128 k
    int f = tid + j * 512;
    int o = f >> 5;
    int i0 = (f & 31) << 2;
    f32x4 v = *reinterpret_cast<const f32x4*>(&W[(size_t)o * ND + i0]);
#pragma unroll
    for (int i2 = 0; i2 < 4; ++i2) {
      int k = i0 + i2;
      wt[k][o ^ (k & 28)] = v[i2];
    }
  }
  __syncthreads();

  const int tc = tid & 31;                 // cols tc*4..+3
  const int tr = tid >> 5;                 // rows tr*4..+3 (0..15)

  float acc[4][4];
#pragma unroll
  for (int r = 0; r < 4; ++r)
#pragma unroll
    for (int c = 0; c < 4; ++c) acc[r][c] = 0.f;

#pragma unroll 4
  for (int k = 0; k < 128; ++k) {
    const int sw = k & 28;
    f32x4 xv = *reinterpret_cast<const f32x4*>(&xs[k][(tr * 4) ^ sw]);
    f32x4 wv = *reinterpret_cast<const f32x4*>(&wt[k][(tc * 4) ^ sw]);
#pragma unroll
    for (int r = 0; r < 4; ++r)
#pragma unroll
      for (int c = 0; c < 4; ++c) acc[r][c] += xv[r] * wv[c];
  }

  f32x4 bv = *reinterpret_cast<const f32x4*>(&bias[tc * 4]);
#pragma unroll
  for (int r = 0; r < 4; ++r)
#pragma unroll
    for (int c = 0; c < 4; ++c) acc[r][c] += bv[c];

  // row L2 norms: reduce across the 32 tc-lanes (half-wave) per row
  float inv[4];
#pragma unroll
  for (int r = 0; r < 4; ++r) {
    float s = acc[r][0] * acc[r][0] + acc[r][1] * acc[r][1] +
              acc[r][2] * acc[r][2] + acc[r][3] * acc[r][3];
#pragma unroll
    for (int d = 1; d < 32; d <<= 1) s += __shfl_xor(s, d, 32);
    inv[r] = 1.f / fmaxf(sqrtf(s), 1e-12f);
  }

#pragma unroll
  for (int r = 0; r < 4; ++r) {            // hn row-major (coalesced 8B stores)
    u16x4 hv;
#pragma unroll
    for (int c = 0; c < 4; ++c) hv[c] = f2bf(acc[r][c] * inv[r]);
    *reinterpret_cast<u16x4*>(&hn[(size_t)(rbase + tr * 4 + r) * ND + tc * 4]) = hv;
  }
#pragma unroll
  for (int c = 0; c < 4; ++c) {            // hT feature-major (8B chunks)
    u16x4 tv;
#pragma unroll
    for (int r = 0; r < 4; ++r) tv[r] = f2bf(acc[r][c]);
    *reinterpret_cast<u16x4*>(
        &hT[((size_t)b * ND + tc * 4 + c) * NN + nb + tr * 4]) = tv;
  }
}

// K2: fused out = relu((edge * (hn hn^T)) @ h).
// 256 blocks (b, qtile64) x 8 waves. Waves 0-3: q rows w*16, keys [0,1024);
// waves 4-7: same q rows, keys [1024,2048). Cross-wave LDS reduce at end.
__global__ __launch_bounds__(512, 2) void k_fused(
    const float* __restrict__ edge,
    const unsigned short* __restrict__ hn,
    const unsigned short* __restrict__ hT,
    float* __restrict__ out) {
  __shared__ __align__(16) unsigned short p_lds[8][16][72];  // per-wave P tile
  __shared__ __align__(16) float red[4][16][128];            // cross-wave reduce
  const int tid = threadIdx.x;
  const int w = tid >> 6;
  const int l = tid & 63;
  const int m = l & 15;     // mfma row/col lane index
  const int g = l >> 4;     // mfma k-group / row-group
  const int wq = w & 3;     // q sub-tile
  const int wk = w >> 2;    // key half

  const int bid = blockIdx.x;   // 256 blocks: same-b blocks adjacent -> L2 reuse
  const int qt = bid & 31;
  const int b = bid >> 5;

  const int q0 = qt * 64 + wq * 16;
  const unsigned short* hnb = hn + (size_t)b * NN * ND;

  // Q fragments: A[m][k], 8 contiguous k per lane
  bf16x8 aq[4];
  {
    const unsigned short* qp = hnb + (size_t)(q0 + m) * ND + g * 8;
#pragma unroll
    for (int kst = 0; kst < 4; ++kst)
      aq[kst] = *reinterpret_cast<const bf16x8*>(qp + kst * 32);
  }

  f32x4 acc_o[8];
#pragma unroll
  for (int i = 0; i < 8; ++i) acc_o[i] = (f32x4){0.f, 0.f, 0.f, 0.f};

  const float* erow = edge + (size_t)b * NN * NN + (size_t)(q0 + g * 4) * NN;
  const unsigned short* vbase = hT + ((size_t)b * ND + m) * NN;

  for (int kt = 0; kt < 16; ++kt) {
    const int kb = wk * 1024 + kt * 64;

    // S = Q K^T  (keys kb..kb+63), fp32 acc
    f32x4 acc_s[4];
#pragma unroll
    for (int ct = 0; ct < 4; ++ct) {
      acc_s[ct] = (f32x4){0.f, 0.f, 0.f, 0.f};
      const unsigned short* kp = hnb + (size_t)(kb + ct * 16 + m) * ND + g * 8;
#pragma unroll
      for (int kst = 0; kst < 4; ++kst) {
        bf16x8 bk = *reinterpret_cast<const bf16x8*>(kp + kst * 32);
        acc_s[ct] =
            __builtin_amdgcn_mfma_f32_16x16x32_bf16(aq[kst], bk, acc_s[ct], 0, 0, 0);
      }
    }

    // gate with edge (streamed from HBM), pack bf16 into per-wave LDS P tile
#pragma unroll
    for (int ct = 0; ct < 4; ++ct) {
      const int key = kb + ct * 16 + m;
#pragma unroll
      for (int r = 0; r < 4; ++r) {
        float e = erow[(size_t)r * NN + key];
        p_lds[w][g * 4 + r][ct * 16 + m] = f2bf(e * acc_s[ct][r]);
      }
    }

    // out += P @ h  (A = P from LDS, B = hT contiguous 16B loads)
#pragma unroll
    for (int kst2 = 0; kst2 < 2; ++kst2) {
      bf16x8 ap =
          *reinterpret_cast<const bf16x8*>(&p_lds[w][m][kst2 * 32 + g * 8]);
      const unsigned short* vp = vbase + kb + kst2 * 32 + g * 8;
#pragma unroll
      for (int ct2 = 0; ct2 < 8; ++ct2) {
        bf16x8 bv2 = *reinterpret_cast<const bf16x8*>(vp + (size_t)ct2 * 16 * NN);
        acc_o[ct2] =
            __builtin_amdgcn_mfma_f32_16x16x32_bf16(ap, bv2, acc_o[ct2], 0, 0, 0);
      }
    }
  }

  // combine key-halves: waves 4-7 stash, waves 0-3 add + relu + store
  if (w >= 4) {
#pragma unroll
    for (int ct2 = 0; ct2 < 8; ++ct2)
#pragma unroll
      for (int r = 0; r < 4; ++r)
        red[wq][g * 4 + r][ct2 * 16 + m] = acc_o[ct2][r];
  }
  __syncthreads();
  if (w < 4) {
    float* ob = out + ((size_t)b * NN + q0) * ND;
#pragma unroll
    for (int ct2 = 0; ct2 < 8; ++ct2)
#pragma unroll
      for (int r = 0; r < 4; ++r) {
        float v = acc_o[ct2][r] + red[wq][g * 4 + r][ct2 * 16 + m];
        ob[(g * 4 + r) * ND + ct2 * 16 + m] = fmaxf(v, 0.f);
      }
  }
}

extern "C" void kernel_launch(void* const* d_in, const int* in_sizes, int n_in,
                              void* d_out, int out_size, void* d_ws, size_t ws_size,
                              hipStream_t stream) {
  const float* x = (const float*)d_in[0];
  const float* edge = (const float*)d_in[1];
  const float* W = (const float*)d_in[2];
  const float* bias = (const float*)d_in[3];
  float* out = (float*)d_out;

  unsigned short* hn = (unsigned short*)d_ws;                 // 4 MB
  unsigned short* hT = hn + (size_t)NB * NN * ND;             // 4 MB

  k_linear<<<dim3((NB * NN) / 64), dim3(512), 0, stream>>>(x, W, bias, hn, hT);
  k_fused<<<dim3(NB * (NN / 64)), dim3(512), 0, stream>>>(edge, hn, hT, out);
}